// Round 1
// baseline (503.026 us; speedup 1.0000x reference)
//
#include <hip/hip_runtime.h>
#include <cmath>

#define NB 1024   // batches
#define NN 1024   // rows
#define MM 64     // cols
#define NT 256    // threads per block

// Block-wide sum over 256 threads (4 waves). Trailing barrier protects s_tmp reuse.
__device__ __forceinline__ float block_sum(float v, float* s_tmp) {
    #pragma unroll
    for (int off = 32; off > 0; off >>= 1) v += __shfl_xor(v, off, 64);
    if ((threadIdx.x & 63) == 0) s_tmp[threadIdx.x >> 6] = v;
    __syncthreads();
    float r = s_tmp[0] + s_tmp[1] + s_tmp[2] + s_tmp[3];
    __syncthreads();
    return r;
}

__device__ __forceinline__ float block_max(float v, float* s_tmp) {
    #pragma unroll
    for (int off = 32; off > 0; off >>= 1) v = fmaxf(v, __shfl_xor(v, off, 64));
    if ((threadIdx.x & 63) == 0) s_tmp[threadIdx.x >> 6] = v;
    __syncthreads();
    float r = fmaxf(fmaxf(s_tmp[0], s_tmp[1]), fmaxf(s_tmp[2], s_tmp[3]));
    __syncthreads();
    return r;
}

__global__ void __launch_bounds__(NT) ntm_fused(
    const float* __restrict__ memory,
    const float* __restrict__ k,
    const float* __restrict__ beta,
    const float* __restrict__ g,
    const float* __restrict__ s,
    const float* __restrict__ gamma,
    const float* __restrict__ w_prev,
    const float* __restrict__ e,
    const float* __restrict__ a,
    float* __restrict__ out)
{
    __shared__ float  s_wg[NN];     // scores, then interpolated wg
    __shared__ float  s_w[NN];      // final sharpened+normalized weights
    __shared__ float  s_k[MM];
    __shared__ float  s_tmp[4];
    __shared__ float4 s_red[NT];

    const int b  = blockIdx.x;
    const int t  = threadIdx.x;
    const int cg = t & 15;   // column group: cols [4*cg, 4*cg+3]
    const int rg = t >> 4;   // row subgroup: 0..15

    const float* memb = memory + (size_t)b * NN * MM;
    float*       outb = out    + (size_t)b * (NN + 1) * MM;

    // --- stage k_e, compute ||k_e|| ---
    if (t < MM) s_k[t] = k[b * MM + t] + 1e-16f;
    __syncthreads();
    float kq = (t < MM) ? s_k[t] * s_k[t] : 0.0f;
    float kden = fmaxf(sqrtf(block_sum(kq, s_tmp)), 1e-8f);
    const float bet = beta[b];
    const float4 k4 = ((const float4*)s_k)[cg];

    // --- pass 1: cosine-sim scores ---
    for (int it = 0; it < NN / 16; ++it) {
        int n = it * 16 + rg;
        float4 m4 = *(const float4*)(memb + n * MM + 4 * cg);
        float ex = m4.x + 1e-16f, ey = m4.y + 1e-16f;
        float ez = m4.z + 1e-16f, ew = m4.w + 1e-16f;
        float d = ex * k4.x + ey * k4.y + ez * k4.z + ew * k4.w;
        float q = ex * ex + ey * ey + ez * ez + ew * ew;
        #pragma unroll
        for (int off = 8; off > 0; off >>= 1) {
            d += __shfl_xor(d, off, 64);
            q += __shfl_xor(q, off, 64);
        }
        if (cg == 0) {
            float denom = fmaxf(sqrtf(q), 1e-8f) * kden;
            s_wg[n] = bet * d / denom;
        }
    }
    __syncthreads();

    // --- softmax over N (each thread owns indices t, t+256, t+512, t+768) ---
    float sc0 = s_wg[t], sc1 = s_wg[t + 256], sc2 = s_wg[t + 512], sc3 = s_wg[t + 768];
    float mx = block_max(fmaxf(fmaxf(sc0, sc1), fmaxf(sc2, sc3)), s_tmp);
    float e0 = __expf(sc0 - mx), e1 = __expf(sc1 - mx);
    float e2 = __expf(sc2 - mx), e3 = __expf(sc3 - mx);
    float inv_esum = 1.0f / block_sum(e0 + e1 + e2 + e3, s_tmp);

    // --- interpolate ---
    const float gb = g[b], omg = 1.0f - gb;
    s_wg[t]       = gb * e0 * inv_esum + omg * w_prev[b * NN + t];
    s_wg[t + 256] = gb * e1 * inv_esum + omg * w_prev[b * NN + t + 256];
    s_wg[t + 512] = gb * e2 * inv_esum + omg * w_prev[b * NN + t + 512];
    s_wg[t + 768] = gb * e3 * inv_esum + omg * w_prev[b * NN + t + 768];
    __syncthreads();

    // --- shift (3-tap circular) + sharpen ---
    const float s0 = s[b * 3 + 0], s1 = s[b * 3 + 1], s2 = s[b * 3 + 2];
    const float gam = gamma[b];
    float wpart = 0.0f;
    #pragma unroll
    for (int j = 0; j < 4; ++j) {
        int n  = t + j * 256;
        int nm = (n == 0) ? NN - 1 : n - 1;
        int np = (n == NN - 1) ? 0 : n + 1;
        float wh = s0 * s_wg[nm] + s1 * s_wg[n] + s2 * s_wg[np];
        float w  = powf(wh, gam);
        s_w[n] = w;
        wpart += w;
    }
    float winv = 1.0f / (block_sum(wpart, s_tmp) + 1e-16f);
    #pragma unroll
    for (int j = 0; j < 4; ++j) s_w[t + j * 256] *= winv;
    __syncthreads();

    // --- pass 2: read + erase/add update ---
    const float4 e4 = *(const float4*)(e + b * MM + 4 * cg);
    const float4 a4 = *(const float4*)(a + b * MM + 4 * cg);
    float4 acc = make_float4(0.f, 0.f, 0.f, 0.f);
    for (int it = 0; it < NN / 16; ++it) {
        int n = it * 16 + rg;
        float4 m4 = *(const float4*)(memb + n * MM + 4 * cg);
        float wn = s_w[n];
        acc.x += wn * m4.x; acc.y += wn * m4.y;
        acc.z += wn * m4.z; acc.w += wn * m4.w;
        float4 o;
        o.x = m4.x * (1.0f - wn * e4.x) + wn * a4.x;
        o.y = m4.y * (1.0f - wn * e4.y) + wn * a4.y;
        o.z = m4.z * (1.0f - wn * e4.z) + wn * a4.z;
        o.w = m4.w * (1.0f - wn * e4.w) + wn * a4.w;
        *(float4*)(outb + (n + 1) * MM + 4 * cg) = o;
    }

    // reduce read accumulator across the 16 row-subgroups per column group
    s_red[t] = acc;
    __syncthreads();
    if (t < 16) {
        float4 r = make_float4(0.f, 0.f, 0.f, 0.f);
        #pragma unroll
        for (int gi = 0; gi < 16; ++gi) {
            float4 v = s_red[gi * 16 + t];
            r.x += v.x; r.y += v.y; r.z += v.z; r.w += v.w;
        }
        *(float4*)(outb + 4 * t) = r;   // row 0 = read
    }
}

extern "C" void kernel_launch(void* const* d_in, const int* in_sizes, int n_in,
                              void* d_out, int out_size, void* d_ws, size_t ws_size,
                              hipStream_t stream) {
    ntm_fused<<<NB, NT, 0, stream>>>(
        (const float*)d_in[0],  // memory (B,N,M)
        (const float*)d_in[1],  // k      (B,M)
        (const float*)d_in[2],  // beta   (B,1)
        (const float*)d_in[3],  // g      (B,1)
        (const float*)d_in[4],  // s      (B,3)
        (const float*)d_in[5],  // gamma  (B,1)
        (const float*)d_in[6],  // w_prev (B,N)
        (const float*)d_in[7],  // e      (B,M)
        (const float*)d_in[8],  // a      (B,M)
        (float*)d_out);
}